// Round 2
// baseline (796.168 us; speedup 1.0000x reference)
//
#include <hip/hip_runtime.h>
#include <hip/hip_cooperative_groups.h>
#include <math.h>

namespace cg = cooperative_groups;

// Problem constants
#define Vv 32000
#define Ee 1024
#define Hh 1024
#define Aa 10
#define Ss 512
#define Bb 64
#define Mm (Ss * Bb)   // 32768 rows of enc viewed as (s*64+b)

#define NBLK 512       // cooperative grid size: 2 blocks/CU on 256 CUs

typedef __attribute__((ext_vector_type(8))) short bf16x8;   // 8 bf16 = 4 VGPRs
typedef __attribute__((ext_vector_type(4))) short s16x4;
typedef __attribute__((ext_vector_type(4))) float f32x4;

// fp32 -> bf16 (round-to-nearest-even), bit trick
__device__ inline short f2bf(float f) {
    union { float f; unsigned int u; } v;
    v.f = f;
    unsigned int r = (v.u + 0x7FFFu + ((v.u >> 16) & 1u)) >> 16;
    return (short)r;
}

__device__ inline bf16x8 cvt8(float4 lo, float4 hi) {
    bf16x8 r;
    r[0] = f2bf(lo.x); r[1] = f2bf(lo.y); r[2] = f2bf(lo.z); r[3] = f2bf(lo.w);
    r[4] = f2bf(hi.x); r[5] = f2bf(hi.y); r[6] = f2bf(hi.z); r[7] = f2bf(hi.w);
    return r;
}

// ---------------------------------------------------------------------------
// Streaming MFMA GEMM phase: C[kp][64][N] = bf16(A)[64][K-slice] @ bf16(W)^T
// Wave w owns 16 cols (n0 = nb*64 + w*16), 64 rows as 4 16x16 tiles.
template<int K, int KLEN>
__device__ __forceinline__ void gemm_phase(const short* __restrict__ Abf,
                                           const float* __restrict__ W,
                                           const float* __restrict__ bias,
                                           float* __restrict__ C, int N,
                                           int nb, int kp, int w, int lane) {
    const int col = lane & 15, quad = lane >> 4;
    const int n0 = nb * 64 + w * 16;
    const int kb0 = kp * KLEN;

    f32x4 acc[4];
#pragma unroll
    for (int mt = 0; mt < 4; mt++) acc[mt] = (f32x4){0.f, 0.f, 0.f, 0.f};

    const float* wrow = W + (size_t)(n0 + col) * K + kb0 + quad * 8;
    const short* arow = Abf + (size_t)col * K + kb0 + quad * 8;

#pragma unroll 2
    for (int kb = 0; kb < KLEN; kb += 64) {
        float4 w0 = *(const float4*)(wrow + kb);
        float4 w1 = *(const float4*)(wrow + kb + 4);
        float4 w2 = *(const float4*)(wrow + kb + 32);
        float4 w3 = *(const float4*)(wrow + kb + 36);
        bf16x8 bf0 = cvt8(w0, w1);
        bf16x8 bf1 = cvt8(w2, w3);
        bf16x8 a0[4], a1[4];
#pragma unroll
        for (int mt = 0; mt < 4; mt++) {
            a0[mt] = *(const bf16x8*)(arow + (size_t)mt * 16 * K + kb);
            a1[mt] = *(const bf16x8*)(arow + (size_t)mt * 16 * K + kb + 32);
        }
#pragma unroll
        for (int mt = 0; mt < 4; mt++)
            acc[mt] = __builtin_amdgcn_mfma_f32_16x16x32_bf16(a0[mt], bf0, acc[mt], 0, 0, 0);
#pragma unroll
        for (int mt = 0; mt < 4; mt++)
            acc[mt] = __builtin_amdgcn_mfma_f32_16x16x32_bf16(a1[mt], bf1, acc[mt], 0, 0, 0);
    }

    const float bv = (bias != nullptr) ? bias[n0 + col] : 0.f;
    float* Cp = C + (size_t)kp * 64 * N;
#pragma unroll
    for (int mt = 0; mt < 4; mt++) {
#pragma unroll
        for (int r = 0; r < 4; r++) {
            int m = mt * 16 + quad * 4 + r;
            Cp[(size_t)m * N + n0 + col] = acc[mt][r] + bv;
        }
    }
}

// ---------------------------------------------------------------------------
// One cooperative kernel for the whole decoder step. 512 blocks x 256 thr,
// 2 blocks/CU co-resident (launch_bounds), grid.sync() between phases.
__global__ __launch_bounds__(256, 2) void mega_kernel(
    const int* __restrict__ dec_input,
    const float* __restrict__ dec_hidden,
    const float* __restrict__ enc,
    const float* __restrict__ emb,
    const float* __restrict__ Wa1,
    const float* __restrict__ Wa2,
    const float* __restrict__ W_ih,
    const float* __restrict__ W_hh,
    const float* __restrict__ b_ih,
    const float* __restrict__ b_hh,
    const float* __restrict__ W_out,
    const float* __restrict__ b_out,
    float* __restrict__ ws,
    float* __restrict__ logits,
    float* __restrict__ h_new) {
    cg::grid_group grid = cg::this_grid();
    const int blk = blockIdx.x;
    const int t = threadIdx.x;
    const int w = t >> 6, lane = t & 63;

    // Workspace layout (floats):
    float* hpart = ws;                    // [64][16]
    float* e_t   = ws + 1024;             // [64][512]
    short* xcb   = (short*)(ws + 33792);  // [64][2048] bf16
    short* hb    = (short*)(ws + 99328);  // [64][1024] bf16
    short* hnb   = (short*)(ws + 132096); // [64][1024] bf16
    float* cpart = ws + 164864;           // [8][64][1024]
    float* gip   = ws + 689152;           // [8][64][3072]
    float* ghp   = ws + 2262016;          // [2][64][3072]

    __shared__ float sm[Ss];
    __shared__ float sred[8];
    __shared__ float part4[4][16];

    // ---- P0: hpart[b][a] = sum_k Wa1[a][k] * h_last[b][k]  (blocks 0..63) ----
    if (blk < Bb) {
        const int b = blk;
        const float* hb_ = dec_hidden + (size_t)b * Hh;
        float p[Aa];
#pragma unroll
        for (int a = 0; a < Aa; a++) p[a] = 0.f;
#pragma unroll
        for (int i = 0; i < 4; i++) {
            const int k = w * 256 + i * 64 + lane;
            const float hv = hb_[k];
#pragma unroll
            for (int a = 0; a < Aa; a++) p[a] += Wa1[a * (2 * Hh) + k] * hv;
        }
#pragma unroll
        for (int a = 0; a < Aa; a++) {
            float v = p[a];
            v += __shfl_xor(v, 1, 64);
            v += __shfl_xor(v, 2, 64);
            v += __shfl_xor(v, 4, 64);
            v += __shfl_xor(v, 8, 64);
            v += __shfl_xor(v, 16, 64);
            v += __shfl_xor(v, 32, 64);
            if (lane == 0) part4[w][a] = v;
        }
        __syncthreads();
        if (t < Aa)
            hpart[b * 16 + t] = part4[0][t] + part4[1][t] + part4[2][t] + part4[3][t];
    }
    grid.sync();

    // ---- P1: scores MFMA + e-reduce, write e_t[b][s] ----
    {
        const int col = lane & 15, quad = lane >> 4;
        const int m0 = (blk * 4 + w) * 16;
        const int bb = m0 & 63;
        const bool valid = (col < Aa);
        const int wa_row = valid ? col : 0;

        const float* erow = enc + (size_t)(m0 + col) * Hh + quad * 8;
        const float* wrow = Wa1 + (size_t)wa_row * (2 * Hh) + Hh + quad * 8;

        f32x4 acc = {0.f, 0.f, 0.f, 0.f};
#pragma unroll 4
        for (int c = 0; c < 32; c++) {
            float4 a0 = *(const float4*)(erow + c * 32);
            float4 a1 = *(const float4*)(erow + c * 32 + 4);
            bf16x8 af = cvt8(a0, a1);
            bf16x8 bf;
            if (valid) {
                float4 b0 = *(const float4*)(wrow + c * 32);
                float4 b1 = *(const float4*)(wrow + c * 32 + 4);
                bf = cvt8(b0, b1);
            } else {
                bf = (bf16x8){0, 0, 0, 0, 0, 0, 0, 0};
            }
            acc = __builtin_amdgcn_mfma_f32_16x16x32_bf16(af, bf, acc, 0, 0, 0);
        }

        const float w2 = valid ? Wa2[col] : 0.f;
        float v[4];
#pragma unroll
        for (int r = 0; r < 4; r++) {
            const int mr = quad * 4 + r;
            const float hp = valid ? hpart[(bb + mr) * 16 + col] : 0.f;
            v[r] = w2 * tanhf(acc[r] + hp);
        }
#pragma unroll
        for (int r = 0; r < 4; r++) {
            v[r] += __shfl_xor(v[r], 1, 16);
            v[r] += __shfl_xor(v[r], 2, 16);
            v[r] += __shfl_xor(v[r], 4, 16);
            v[r] += __shfl_xor(v[r], 8, 16);
        }
        if (col == 0) {
#pragma unroll
            for (int r = 0; r < 4; r++) {
                const int m = m0 + quad * 4 + r;
                e_t[(size_t)(m & 63) * Ss + (m >> 6)] = v[r];
            }
        }
    }
    grid.sync();

    // ---- P2: softmax recompute + context partials ----
    // block = (b = blk&63, sc = blk>>6 in [0,8)), 64-s chunk each
    {
        const int b = blk & 63, sc = blk >> 6;
        const float x0 = e_t[(size_t)b * Ss + t];
        const float x1 = e_t[(size_t)b * Ss + 256 + t];
        float mx = fmaxf(x0, x1);
        mx = fmaxf(mx, __shfl_xor(mx, 1, 64));
        mx = fmaxf(mx, __shfl_xor(mx, 2, 64));
        mx = fmaxf(mx, __shfl_xor(mx, 4, 64));
        mx = fmaxf(mx, __shfl_xor(mx, 8, 64));
        mx = fmaxf(mx, __shfl_xor(mx, 16, 64));
        mx = fmaxf(mx, __shfl_xor(mx, 32, 64));
        if (lane == 0) sred[w] = mx;
        __syncthreads();
        const float MX = fmaxf(fmaxf(sred[0], sred[1]), fmaxf(sred[2], sred[3]));
        const float e0 = expf(x0 - MX), e1 = expf(x1 - MX);
        sm[t] = e0;
        sm[t + 256] = e1;
        float su = e0 + e1;
        su += __shfl_xor(su, 1, 64);
        su += __shfl_xor(su, 2, 64);
        su += __shfl_xor(su, 4, 64);
        su += __shfl_xor(su, 8, 64);
        su += __shfl_xor(su, 16, 64);
        su += __shfl_xor(su, 32, 64);
        if (lane == 0) sred[4 + w] = su;
        __syncthreads();
        const float inv = 1.f / (sred[4] + sred[5] + sred[6] + sred[7]);

        const float4* enc4 = (const float4*)enc;
        float4 acc = {0.f, 0.f, 0.f, 0.f};
        const int s0 = sc * 64;
#pragma unroll 4
        for (int i = 0; i < 64; ++i) {
            const int s = s0 + i;
            const float a = sm[s] * inv;
            float4 ev = enc4[(size_t)(s * Bb + b) * 256 + t];
            acc.x += a * ev.x;
            acc.y += a * ev.y;
            acc.z += a * ev.z;
            acc.w += a * ev.w;
        }
        ((float4*)cpart)[((size_t)sc * Bb + b) * 256 + t] = acc;
    }
    grid.sync();

    // ---- P3: xc build (blocks 0..63): reduce 8 cparts, emit bf16 operands ----
    if (blk < Bb) {
        const int b = blk;
        const int tok = dec_input[b];
        float4 cv = {0.f, 0.f, 0.f, 0.f};
#pragma unroll
        for (int p = 0; p < 8; p++) {
            float4 v = ((const float4*)cpart)[((size_t)p * Bb + b) * 256 + t];
            cv.x += v.x; cv.y += v.y; cv.z += v.z; cv.w += v.w;
        }
        float4 ev = ((const float4*)(emb + (size_t)tok * Ee))[t];
        float4 hv = ((const float4*)(dec_hidden + (size_t)b * Hh))[t];
        s16x4 e4 = {f2bf(ev.x), f2bf(ev.y), f2bf(ev.z), f2bf(ev.w)};
        s16x4 c4 = {f2bf(cv.x), f2bf(cv.y), f2bf(cv.z), f2bf(cv.w)};
        s16x4 h4v = {f2bf(hv.x), f2bf(hv.y), f2bf(hv.z), f2bf(hv.w)};
        ((s16x4*)(xcb + (size_t)b * 2048))[t] = e4;
        ((s16x4*)(xcb + (size_t)b * 2048 + 1024))[t] = c4;
        ((s16x4*)(hb + (size_t)b * 1024))[t] = h4v;
    }
    grid.sync();

    // ---- P4: gi = xc @ W_ih^T (384 tasks, ksplit 8), gh = h @ W_hh^T (96, ksplit 2)
    if (blk < 384) {
        gemm_phase<2048, 256>(xcb, W_ih, nullptr, gip, 3 * Hh, blk % 48, blk / 48, w, lane);
    } else if (blk < 480) {
        const int t2 = blk - 384;
        gemm_phase<1024, 512>(hb, W_hh, nullptr, ghp, 3 * Hh, t2 % 48, t2 / 48, w, lane);
    }
    grid.sync();

    // ---- P5: GRU elementwise (512 blocks x 128 elems) ----
    if (t < 128) {
        const int idx = blk * 128 + t;
        const int b = idx >> 10, j = idx & 1023;
        const size_t base = (size_t)b * (3 * Hh);
        float ir = b_ih[j], iz = b_ih[Hh + j], in_ = b_ih[2 * Hh + j];
        float hr = b_hh[j], hz = b_hh[Hh + j], hn = b_hh[2 * Hh + j];
#pragma unroll
        for (int p = 0; p < 8; p++) {
            const float* g = gip + (size_t)p * Bb * 3 * Hh + base;
            ir += g[j]; iz += g[Hh + j]; in_ += g[2 * Hh + j];
        }
#pragma unroll
        for (int p = 0; p < 2; p++) {
            const float* g = ghp + (size_t)p * Bb * 3 * Hh + base;
            hr += g[j]; hz += g[Hh + j]; hn += g[2 * Hh + j];
        }
        float r = 1.f / (1.f + expf(-(ir + hr)));
        float z = 1.f / (1.f + expf(-(iz + hz)));
        float n = tanhf(in_ + r * hn);
        float val = (1.f - z) * n + z * dec_hidden[idx];
        h_new[idx] = val;
        hnb[idx] = f2bf(val);
    }
    grid.sync();

    // ---- P6: logits = h_new @ W_out^T + b_out (500 tasks) ----
    if (blk < Vv / 64) {
        gemm_phase<1024, 1024>(hnb, W_out, b_out, logits, Vv, blk, 0, w, lane);
    }
}

// ---------------------------------------------------------------------------
extern "C" void kernel_launch(void* const* d_in, const int* in_sizes, int n_in,
                              void* d_out, int out_size, void* d_ws, size_t ws_size,
                              hipStream_t stream) {
    const int* dec_input = (const int*)d_in[0];
    const float* dec_hidden = (const float*)d_in[1];
    const float* enc = (const float*)d_in[2];
    const float* emb = (const float*)d_in[3];
    const float* Wa1 = (const float*)d_in[4];
    const float* Wa2 = (const float*)d_in[5];
    const float* W_ih = (const float*)d_in[6];
    const float* W_hh = (const float*)d_in[7];
    const float* b_ih = (const float*)d_in[8];
    const float* b_hh = (const float*)d_in[9];
    const float* W_out = (const float*)d_in[10];
    const float* b_out = (const float*)d_in[11];

    float* out = (float*)d_out;
    float* logits = out;                  // (B,V)
    float* h_new = out + (size_t)Bb * Vv; // (1,B,H)
    float* ws = (float*)d_ws;

    void* args[] = {
        (void*)&dec_input, (void*)&dec_hidden, (void*)&enc, (void*)&emb,
        (void*)&Wa1, (void*)&Wa2, (void*)&W_ih, (void*)&W_hh,
        (void*)&b_ih, (void*)&b_hh, (void*)&W_out, (void*)&b_out,
        (void*)&ws, (void*)&logits, (void*)&h_new
    };
    hipLaunchCooperativeKernel((void*)mega_kernel, dim3(NBLK), dim3(256),
                               args, 0, stream);
}